// Round 17
// baseline (202.249 us; speedup 1.0000x reference)
//
#include <hip/hip_runtime.h>
#include <cstddef>
#include <cstdint>

namespace {

constexpr int   kN = 512;
constexpr int   kB = 64;
constexpr float kAlpha = 0.8f;
constexpr float kKexp = 144.26950408889634f;    // (1/gamma) * log2(e)
constexpr float kGLn2 = 0.006931471805599453f;  // gamma * ln(2) = 1/kKexp
constexpr float kWexp = 0.07213475204444817f;   // G * log2(e)
constexpr float kZBig = -1.4426950408889634e10f; // -kKexp * 1e8 (BIG in z-units)

constexpr int W     = 8;     // waves per block (2 per SIMD)
constexpr int DELTA = 8;     // global steps between block barriers
constexpr int LAM   = 72;    // per-wave lag (63 skew + DELTA + 1)
constexpr int SMAX  = 574;   // last local step per wave (inclusive)
constexpr int NSUP  = 135;   // supersteps cover g = 0..1079 >= 1078
constexpr int BUFE  = 592;   // boundary buffer entries per band (no wrap)

// result lane i = src[i-1] for i>=1; lane 0 = oldv[0]  (wave_shr:1 fold)
__device__ __forceinline__ float dpp_oldshr1(float oldv, float src) {
    const int oi = __builtin_bit_cast(int, oldv);
    const int si = __builtin_bit_cast(int, src);
    const int r  = __builtin_amdgcn_update_dpp(oi, si, 0x138, 0xF, 0xF, false);
    return __builtin_bit_cast(float, r);
}

// Single forward pass computing (z, Rdot) where z = -k*R (k=1/gamma*log2e) and
// Rdot = JVP of soft-DTW in direction Omega_ij=(i-j)^2. In z-units softmin is
// a softmax: z_sm = zmax + log2(ss), ss = sum 2^(zX - zmax), and the cell
// update is zcur = wkz*dx^2 + zmax + log2(ss) (wkz = -k*wk). Duals are
// scale-invariant (weights eX/ss). 8 staggered waves per batch; wave w owns
// rows [64w,64w+64); lane u owns row 64w+u; local step s handles col c = s-u.
// Wave w reads boundary buf[w] (buf[0] prefilled border), writes buf[w+1]
// (all-lane writes; lane63's canonical value lands last, consumer reads one
// superstep later -> exactly one barrier between, race-free).
// x pipeline depth 2: index s+2-u.
__global__ __launch_bounds__(512, 2)
void dilate_jvp8(const float* __restrict__ input,
                 const float* __restrict__ target,
                 float* __restrict__ partials,
                 int b0)
{
    __shared__ float  sx[kN + 16];
    __shared__ float2 buf[W + 1][BUFE];
    __shared__ float  sred[W];

    const int tid = (int)threadIdx.x;
    const int w = tid >> 6, u = tid & 63;
    const bool topw = (w == 0);
    const int b = b0 + (int)blockIdx.x;
    const int sOff = w * LAM;

    sx[tid] = input[(size_t)b * kN + tid];
    if (tid < 16) sx[kN + tid] = 0.0f;
    for (int i = tid; i < BUFE; i += 512) buf[0][i] = make_float2(kZBig, 0.0f);
    const float tk = target[(size_t)b * kN + tid];

    // normalized exponential time weight for row tid (z-folded: wkz = -k*wk)
    float ew = exp2f(kWexp * (float)tid);
    float es = ew;
    #pragma unroll
    for (int off = 32; off; off >>= 1) es += __shfl_xor(es, off);
    if (u == 0) sred[w] = es;
    __syncthreads();
    float tot = 0.0f;
    #pragma unroll
    for (int q = 0; q < W; ++q) tot += sred[q];
    const float wkz = ew * (512.0f / tot) * (-kKexp);

    // ================= forward soft-DTW with dual (JVP), z-space ============
    float C0 = kZBig, C0d = 0.0f;                // own row, previous column
    float bval = kZBig, bvald = 0.0f;            // B: lane0=buf[s], else cur[u-1]
    float aval = (topw && u == 0) ? 0.0f : kZBig;// A: rolls from bval
    float avald = 0.0f;
    float xj = sx[0], xjn = sx[(u == 0) ? 1 : 0];
    float fdr = (float)(64 * w + 2 * u);         // i - j, -1 per slot
    const float2* __restrict__ bufP = buf[w];
    float2* __restrict__ bufN = buf[w + 1];

    for (int m = 0; m < NSUP; ++m) {
        const int base = m * DELTA - sOff;
        if (base >= 64 && base <= 504) {
            // ---------- FULL: every lane valid for all 8 slots ----------
            #pragma unroll
            for (int dg = 0; dg < DELTA; ++dg) {
                const int s = base + dg;
                const float zm = fmaxf(bval, fmaxf(aval, C0));
                const float eA = exp2f(aval - zm);
                const float eB = exp2f(bval - zm);
                const float eC = exp2f(C0   - zm);
                const float ss = eA + eB + eC;
                const float ri = __builtin_amdgcn_rcpf(ss);
                const float dx = tk - xj;
                const float zcur = fmaf(wkz * dx, dx, zm + __log2f(ss));
                const float sd = fmaf(eA, avald, fmaf(eB, bvald, eC * C0d));
                const float curd = fmaf(ri, sd, fdr * fdr);
                C0 = zcur; C0d = curd;
                bufN[s - u] = make_float2(zcur, curd);
                aval = bval; avald = bvald;
                const float2 rn = bufP[s + 1];
                bval  = dpp_oldshr1(rn.x, zcur);
                bvald = dpp_oldshr1(rn.y, curd);
                xj = xjn;
                xjn = sx[s + 2 - u];
                fdr -= 1.0f;
            }
        } else if (base >= -DELTA && base <= SMAX) {
            // ---------- CHECKED: entry/exit ramps ----------
            #pragma unroll
            for (int dg = 0; dg < DELTA; ++dg) {
                const int s = base + dg;
                if (s == -1) {
                    const float2 r0 = bufP[0];
                    bval  = dpp_oldshr1(r0.x, kZBig);
                    bvald = dpp_oldshr1(r0.y, 0.0f);
                } else if (s >= 0 && s <= SMAX) {
                    const int c = s - u;
                    const bool valid = (c >= 0) & (c <= 511);
                    const float zm = fmaxf(bval, fmaxf(aval, C0));
                    const float eA = exp2f(aval - zm);
                    const float eB = exp2f(bval - zm);
                    const float eC = exp2f(C0   - zm);
                    const float ss = eA + eB + eC;
                    const float ri = __builtin_amdgcn_rcpf(ss);
                    const float dx = tk - xj;
                    float zcur = fmaf(wkz * dx, dx, zm + __log2f(ss));
                    const float sd = fmaf(eA, avald, fmaf(eB, bvald, eC * C0d));
                    float curd = fmaf(ri, sd, fdr * fdr);
                    zcur = valid ? zcur : kZBig;
                    curd = valid ? curd : 0.0f;
                    C0 = zcur; C0d = curd;
                    if (c >= 0) bufN[c] = make_float2(zcur, curd);
                    aval = bval; avald = bvald;
                    const float2 rn = bufP[s + 1];
                    bval  = dpp_oldshr1(rn.x, zcur);
                    bvald = dpp_oldshr1(rn.y, curd);
                    xj = xjn;
                    int cc = s + 2 - u;
                    cc = cc < 0 ? 0 : (cc > 511 ? 511 : cc);
                    xjn = sx[cc];
                    fdr -= 1.0f;
                }
            }
        }
        __syncthreads();
    }

    // tid 511 (wave 7, lane 63) holds z[512][512] and Rdot[512][512]
    if (tid == 511) {
        const float rnn = C0 * (-kGLn2);          // R = -z * gamma*ln2
        const float temporal = C0d * (1.0f / (512.0f * 512.0f));
        partials[b] = (kAlpha * rnn + (1.0f - kAlpha) * temporal)
                    * (1.0f / (float)kB);
    }
}

__global__ void dilate_finalize(const float* __restrict__ partials,
                                float* __restrict__ out) {
    float v = partials[threadIdx.x];   // 64 threads = one wave
    #pragma unroll
    for (int off = 32; off > 0; off >>= 1) v += __shfl_down(v, off);
    if (threadIdx.x == 0) out[0] = v;
}

} // namespace

extern "C" void kernel_launch(void* const* d_in, const int* in_sizes, int n_in,
                              void* d_out, int out_size, void* d_ws, size_t ws_size,
                              hipStream_t stream) {
    (void)in_sizes; (void)n_in; (void)out_size; (void)ws_size;
    const float* input  = (const float*)d_in[0];
    const float* target = (const float*)d_in[1];
    float* out      = (float*)d_out;
    float* partials = (float*)d_ws;    // kB floats

    hipLaunchKernelGGL(dilate_jvp8, dim3(kB), dim3(512), 0, stream,
                       input, target, partials, 0);
    hipLaunchKernelGGL(dilate_finalize, dim3(1), dim3(64), 0, stream,
                       partials, out);
}